// Round 1
// baseline (1462.708 us; speedup 1.0000x reference)
//
#include <hip/hip_runtime.h>

// Problem constants (fixed by the reference's setup_inputs)
#define BATCH   256
#define N_PER   4096
#define M_TOTAL (BATCH * N_PER)
#define EMBED   16
#define HID     32
#define NOTE    64
#define LSTM_D  64
#define T_LEN   128
#define LVLS    6

// ---------------------------------------------------------------------------
// Init: compute h for kind==0 (leaf MLP) and kind==1 (ptr matvec) nodes and
// scatter-add into acc[parent]. kind==2 nodes contribute 0 -> skipped.
// One 32-lane group per node; lane j owns output dim j.
// ---------------------------------------------------------------------------
__global__ __launch_bounds__(256) void init_kernel(
    const int* __restrict__ kind, const int* __restrict__ parent,
    const int* __restrict__ tok_a, const int* __restrict__ tok_b,
    const int* __restrict__ ptr_time,
    const float* __restrict__ first_notes, const float* __restrict__ lstm_out,
    const float* __restrict__ embedding,
    const float* __restrict__ leaf_w1, const float* __restrict__ leaf_b1,
    const float* __restrict__ leaf_w2, const float* __restrict__ leaf_b2,
    const float* __restrict__ ptr_w, const float* __restrict__ ptr_b,
    float* __restrict__ acc)
{
    int g    = (blockIdx.x * blockDim.x + threadIdx.x) >> 5;   // node id
    int lane = threadIdx.x & 31;
    if (g >= M_TOTAL) return;
    int k = kind[g];
    if (k == 2) return;   // h = 0, no contribution

    float h;
    if (k == 0) {
        // leaf: (pair @ W1 + b1) @ W2 + b2   (no relu)
        const float* ea = embedding + (size_t)tok_a[g] * EMBED;
        const float* eb = embedding + (size_t)tok_b[g] * EMBED;
        float hid = leaf_b1[lane];
        #pragma unroll
        for (int kk = 0; kk < EMBED; ++kk) hid += ea[kk] * leaf_w1[kk * HID + lane];
        #pragma unroll
        for (int kk = 0; kk < EMBED; ++kk) hid += eb[kk] * leaf_w1[(EMBED + kk) * HID + lane];
        h = leaf_b2[lane];
        #pragma unroll
        for (int kk = 0; kk < HID; ++kk) {
            float hk = __shfl(hid, kk, 32);
            h += hk * leaf_w2[kk * HID + lane];
        }
    } else {
        // ptr: [first_notes[tree], lstm_out[tree, t]] @ ptr_w + b  (no relu)
        int tree = g / N_PER;
        int t    = ptr_time[g];
        const float* fn = first_notes + (size_t)tree * NOTE;
        const float* lo = lstm_out + ((size_t)tree * T_LEN + t) * LSTM_D;
        float v = ptr_b[lane];
        #pragma unroll
        for (int kk = 0; kk < NOTE; ++kk)   v += fn[kk] * ptr_w[kk * HID + lane];
        #pragma unroll
        for (int kk = 0; kk < LSTM_D; ++kk) v += lo[kk] * ptr_w[(NOTE + kk) * HID + lane];
        h = v;
    }
    int p = parent[g];
    atomicAdd(&acc[(size_t)p * HID + lane], h);
}

// ---------------------------------------------------------------------------
// One level pass: nodes with height==lvl compute
//   h = relu([emb_a, emb_b, acc[self]] @ node_w + node_b)
// then scatter-add h into acc[parent] (or store root h at lvl==LVLS).
// ---------------------------------------------------------------------------
__global__ __launch_bounds__(256) void level_kernel(
    const int* __restrict__ height, const int* __restrict__ parent,
    const int* __restrict__ tok_a, const int* __restrict__ tok_b,
    const float* __restrict__ embedding,
    const float* __restrict__ node_w, const float* __restrict__ node_b,
    float* __restrict__ acc, float* __restrict__ roots_h, int lvl)
{
    int g    = (blockIdx.x * blockDim.x + threadIdx.x) >> 5;
    int lane = threadIdx.x & 31;
    if (g >= M_TOTAL) return;
    if (height[g] != lvl) return;

    const float* ea = embedding + (size_t)tok_a[g] * EMBED;
    const float* eb = embedding + (size_t)tok_b[g] * EMBED;
    const float* cs = acc + (size_t)g * HID;

    float v = node_b[lane];
    #pragma unroll
    for (int kk = 0; kk < EMBED; ++kk) v += ea[kk] * node_w[kk * HID + lane];
    #pragma unroll
    for (int kk = 0; kk < EMBED; ++kk) v += eb[kk] * node_w[(EMBED + kk) * HID + lane];
    #pragma unroll
    for (int kk = 0; kk < HID; ++kk)   v += cs[kk] * node_w[(2 * EMBED + kk) * HID + lane];
    v = fmaxf(v, 0.0f);

    if (lvl == LVLS && (g % N_PER) == 0) {
        roots_h[(size_t)(g / N_PER) * HID + lane] = v;   // root: feed the FF head
    } else {
        atomicAdd(&acc[(size_t)parent[g] * HID + lane], v);
    }
}

// ---------------------------------------------------------------------------
// FF head over roots: out[b] = ((r @ W1 + b1) @ W2 + b2) @ tail_w + tail_b
// ---------------------------------------------------------------------------
__global__ __launch_bounds__(256) void final_kernel(
    const float* __restrict__ roots_h,
    const float* __restrict__ ff_w1, const float* __restrict__ ff_b1,
    const float* __restrict__ ff_w2, const float* __restrict__ ff_b2,
    const float* __restrict__ tail_w, const float* __restrict__ tail_b,
    float* __restrict__ out)
{
    int g    = (blockIdx.x * blockDim.x + threadIdx.x) >> 5;   // tree id
    int lane = threadIdx.x & 31;
    if (g >= BATCH) return;
    const float* r = roots_h + (size_t)g * HID;

    float f1 = ff_b1[lane];
    #pragma unroll
    for (int kk = 0; kk < HID; ++kk) f1 += r[kk] * ff_w1[kk * HID + lane];

    float f2 = ff_b2[lane];
    #pragma unroll
    for (int kk = 0; kk < HID; ++kk) f2 += __shfl(f1, kk, 32) * ff_w2[kk * HID + lane];

    float contrib = f2 * tail_w[lane];
    #pragma unroll
    for (int off = 16; off > 0; off >>= 1) contrib += __shfl_down(contrib, off, 32);
    if (lane == 0) out[g] = contrib + tail_b[0];
}

extern "C" void kernel_launch(void* const* d_in, const int* in_sizes, int n_in,
                              void* d_out, int out_size, void* d_ws, size_t ws_size,
                              hipStream_t stream) {
    const int*   kind        = (const int*)d_in[0];
    const int*   height      = (const int*)d_in[1];
    const int*   parent      = (const int*)d_in[2];
    const int*   tok_a       = (const int*)d_in[3];
    const int*   tok_b       = (const int*)d_in[4];
    const int*   ptr_time    = (const int*)d_in[5];
    const float* first_notes = (const float*)d_in[6];
    const float* lstm_out    = (const float*)d_in[7];
    const float* embedding   = (const float*)d_in[8];
    const float* leaf_w1     = (const float*)d_in[9];
    const float* leaf_b1     = (const float*)d_in[10];
    const float* leaf_w2     = (const float*)d_in[11];
    const float* leaf_b2     = (const float*)d_in[12];
    const float* node_w      = (const float*)d_in[13];
    const float* node_b      = (const float*)d_in[14];
    const float* ptr_w       = (const float*)d_in[15];
    const float* ptr_b       = (const float*)d_in[16];
    const float* ff_w1       = (const float*)d_in[17];
    const float* ff_b1       = (const float*)d_in[18];
    const float* ff_w2       = (const float*)d_in[19];
    const float* ff_b2       = (const float*)d_in[20];
    const float* tail_w      = (const float*)d_in[21];
    const float* tail_b      = (const float*)d_in[22];

    float* acc     = (float*)d_ws;                       // [M_TOTAL, HID] fp32
    float* roots_h = acc + (size_t)M_TOTAL * HID;        // [BATCH, HID]

    // acc must be zero every call (ws is re-poisoned to 0xAA before each launch)
    hipMemsetAsync(acc, 0, (size_t)M_TOTAL * HID * sizeof(float), stream);

    const int threads = 256;
    const int groups_per_block = threads / 32;
    const int nblocks = (M_TOTAL + groups_per_block - 1) / groups_per_block;

    init_kernel<<<nblocks, threads, 0, stream>>>(
        kind, parent, tok_a, tok_b, ptr_time,
        first_notes, lstm_out, embedding,
        leaf_w1, leaf_b1, leaf_w2, leaf_b2, ptr_w, ptr_b, acc);

    for (int lvl = 1; lvl <= LVLS; ++lvl) {
        level_kernel<<<nblocks, threads, 0, stream>>>(
            height, parent, tok_a, tok_b, embedding,
            node_w, node_b, acc, roots_h, lvl);
    }

    final_kernel<<<(BATCH * 32 + threads - 1) / threads, threads, 0, stream>>>(
        roots_h, ff_w1, ff_b1, ff_w2, ff_b2, tail_w, tail_b, (float*)d_out);
}

// Round 2
// 701.642 us; speedup vs baseline: 2.0847x; 2.0847x over previous
//
#include <hip/hip_runtime.h>

// Problem constants (fixed by the reference's setup_inputs)
#define BATCH   256
#define N_PER   4096
#define M_TOTAL (BATCH * N_PER)
#define EMBED   16
#define HID     32
#define NOTE    64
#define LSTM_D  64
#define T_LEN   128
#define LVLS    6

// ---------------------------------------------------------------------------
// ws layout (ints), then h array:
//   meta[0..5]  : count of internal nodes at level 1..6 (per tree)
//   meta[6]     : count of kind-0 leaves (per tree)
//   meta[7]     : count of kind-1 ptr nodes (per tree)
//   lvl_lists   : meta+8,            6*4096 ints (local node ids per level)
//   k0_list     : meta+8+6*4096,     4096
//   k1_list     : +4096,             4096
//   child_off   : +4096,             4097  (CSR offsets, one tree)
//   child_idx   : +4097,             4096  (CSR child ids, one tree)
//   h           : at byte offset 256 KiB, [M_TOTAL][HID] fp32
// ---------------------------------------------------------------------------
#define OFF_LVL   8
#define OFF_K0    (OFF_LVL + 6 * N_PER)
#define OFF_K1    (OFF_K0 + N_PER)
#define OFF_COFF  (OFF_K1 + N_PER)
#define OFF_CIDX  (OFF_COFF + N_PER + 1)
#define H_BYTE_OFF (256 * 1024)

// ---------------------------------------------------------------------------
// Build per-tree structure: level lists, leaf lists, children CSR.
// Single block of 1024 threads; tree structure is identical across the batch.
// ---------------------------------------------------------------------------
__global__ __launch_bounds__(1024) void build_structure(
    const int* __restrict__ kind, const int* __restrict__ height,
    const int* __restrict__ parent, int* __restrict__ meta)
{
    __shared__ int cnt[8];
    __shared__ int deg[N_PER];   // 16 KB; later reused as offsets/cursor
    __shared__ int part[1024];

    int t = threadIdx.x;
    if (t < 8) cnt[t] = 0;
    #pragma unroll
    for (int i = t; i < N_PER; i += 1024) deg[i] = 0;
    __syncthreads();

    // bucket nodes + count children degrees (first tree only)
    #pragma unroll
    for (int i = t; i < N_PER; i += 1024) {
        int hgt = height[i];
        int knd = kind[i];
        int bucket;
        if (hgt > 0) bucket = hgt - 1;            // internal, level hgt (1..6)
        else         bucket = (knd == 0) ? 6 : 7; // leaf by kind
        int pos = atomicAdd(&cnt[bucket], 1);
        if (bucket < 6)      meta[OFF_LVL + bucket * N_PER + pos] = i;
        else if (bucket == 6) meta[OFF_K0 + pos] = i;
        else                  meta[OFF_K1 + pos] = i;
        if (i != 0) atomicAdd(&deg[parent[i]], 1);   // skip root self-loop
    }
    __syncthreads();

    // exclusive prefix sum over deg[4096]: 4 elems/thread + block scan
    int base = 4 * t;
    int d0 = deg[base], d1 = deg[base + 1], d2 = deg[base + 2], d3 = deg[base + 3];
    int s = d0 + d1 + d2 + d3;
    part[t] = s;
    __syncthreads();
    for (int off = 1; off < 1024; off <<= 1) {
        int v = (t >= off) ? part[t - off] : 0;
        __syncthreads();
        part[t] += v;
        __syncthreads();
    }
    int ex = (t > 0) ? part[t - 1] : 0;   // exclusive prefix of this thread's chunk
    int o0 = ex, o1 = ex + d0, o2 = o1 + d1, o3 = o2 + d2;
    deg[base] = o0; deg[base + 1] = o1; deg[base + 2] = o2; deg[base + 3] = o3;
    meta[OFF_COFF + base]     = o0;
    meta[OFF_COFF + base + 1] = o1;
    meta[OFF_COFF + base + 2] = o2;
    meta[OFF_COFF + base + 3] = o3;
    if (t == 1023) meta[OFF_COFF + N_PER] = o3 + d3;
    __syncthreads();

    // fill CSR using deg[] as cursor
    #pragma unroll
    for (int i = t; i < N_PER; i += 1024) {
        if (i == 0) continue;
        int pos = atomicAdd(&deg[parent[i]], 1);
        meta[OFF_CIDX + pos] = i;
    }
    if (t < 8) meta[t] = cnt[t];
}

// ---------------------------------------------------------------------------
// Init: compute h for leaf (kind 0) and ptr (kind 1) nodes from compact lists.
// One 32-lane group per node; grid-stride over device-side counts.
// ---------------------------------------------------------------------------
__global__ __launch_bounds__(256) void init_kernel(
    const int* __restrict__ meta,
    const int* __restrict__ tok_a, const int* __restrict__ tok_b,
    const int* __restrict__ ptr_time,
    const float* __restrict__ first_notes, const float* __restrict__ lstm_out,
    const float* __restrict__ embedding,
    const float* __restrict__ leaf_w1, const float* __restrict__ leaf_b1,
    const float* __restrict__ leaf_w2, const float* __restrict__ leaf_b2,
    const float* __restrict__ ptr_w, const float* __restrict__ ptr_b,
    float* __restrict__ h)
{
    int c0 = meta[6], c1 = meta[7];
    int ngroups = (gridDim.x * blockDim.x) >> 5;
    int gid     = (blockIdx.x * blockDim.x + threadIdx.x) >> 5;
    int lane    = threadIdx.x & 31;

    const int* k0_list = meta + OFF_K0;
    const int* k1_list = meta + OFF_K1;

    int tot0 = c0 * BATCH;
    for (int it = gid; it < tot0; it += ngroups) {
        int tree = it / c0;
        int j    = it - tree * c0;
        int gn   = tree * N_PER + k0_list[j];
        const float* ea = embedding + (size_t)tok_a[gn] * EMBED;
        const float* eb = embedding + (size_t)tok_b[gn] * EMBED;
        float hid = leaf_b1[lane];
        #pragma unroll
        for (int kk = 0; kk < EMBED; ++kk) hid += ea[kk] * leaf_w1[kk * HID + lane];
        #pragma unroll
        for (int kk = 0; kk < EMBED; ++kk) hid += eb[kk] * leaf_w1[(EMBED + kk) * HID + lane];
        float v = leaf_b2[lane];
        #pragma unroll
        for (int kk = 0; kk < HID; ++kk) v += __shfl(hid, kk, 32) * leaf_w2[kk * HID + lane];
        h[(size_t)gn * HID + lane] = v;
    }

    int tot1 = c1 * BATCH;
    for (int it = gid; it < tot1; it += ngroups) {
        int tree = it / c1;
        int j    = it - tree * c1;
        int gn   = tree * N_PER + k1_list[j];
        int tt   = ptr_time[gn];
        const float* fn = first_notes + (size_t)tree * NOTE;
        const float* lo = lstm_out + ((size_t)tree * T_LEN + tt) * LSTM_D;
        float v = ptr_b[lane];
        #pragma unroll
        for (int kk = 0; kk < NOTE; ++kk)   v += fn[kk] * ptr_w[kk * HID + lane];
        #pragma unroll
        for (int kk = 0; kk < LSTM_D; ++kk) v += lo[kk] * ptr_w[(NOTE + kk) * HID + lane];
        h[(size_t)gn * HID + lane] = v;
    }
}

// ---------------------------------------------------------------------------
// Level pass (gather form): for nodes at height==lvl,
//   h = relu([emb_a, emb_b, sum_children h] @ node_w + node_b)
// ---------------------------------------------------------------------------
__global__ __launch_bounds__(256) void level_kernel(
    const int* __restrict__ meta,
    const int* __restrict__ tok_a, const int* __restrict__ tok_b,
    const float* __restrict__ embedding,
    const float* __restrict__ node_w, const float* __restrict__ node_b,
    float* __restrict__ h, int lvl)
{
    int cnt = meta[lvl - 1];
    int tot = cnt * BATCH;
    int ngroups = (gridDim.x * blockDim.x) >> 5;
    int gid     = (blockIdx.x * blockDim.x + threadIdx.x) >> 5;
    int lane    = threadIdx.x & 31;

    const int* lvl_list  = meta + OFF_LVL + (lvl - 1) * N_PER;
    const int* child_off = meta + OFF_COFF;
    const int* child_idx = meta + OFF_CIDX;

    for (int it = gid; it < tot; it += ngroups) {
        int tree = it / cnt;
        int j    = it - tree * cnt;
        int node = lvl_list[j];
        int gn   = tree * N_PER + node;

        const float* hb = h + (size_t)tree * N_PER * HID;
        float csum = 0.0f;
        int e = child_off[node], e1 = child_off[node + 1];
        for (; e + 3 < e1; e += 4) {
            float a0 = hb[(size_t)child_idx[e]     * HID + lane];
            float a1 = hb[(size_t)child_idx[e + 1] * HID + lane];
            float a2 = hb[(size_t)child_idx[e + 2] * HID + lane];
            float a3 = hb[(size_t)child_idx[e + 3] * HID + lane];
            csum += (a0 + a1) + (a2 + a3);
        }
        for (; e < e1; ++e) csum += hb[(size_t)child_idx[e] * HID + lane];

        const float* ea = embedding + (size_t)tok_a[gn] * EMBED;
        const float* eb = embedding + (size_t)tok_b[gn] * EMBED;
        float v = node_b[lane];
        #pragma unroll
        for (int kk = 0; kk < EMBED; ++kk) v += ea[kk] * node_w[kk * HID + lane];
        #pragma unroll
        for (int kk = 0; kk < EMBED; ++kk) v += eb[kk] * node_w[(EMBED + kk) * HID + lane];
        #pragma unroll
        for (int kk = 0; kk < HID; ++kk)
            v += __shfl(csum, kk, 32) * node_w[(2 * EMBED + kk) * HID + lane];
        v = fmaxf(v, 0.0f);
        h[(size_t)gn * HID + lane] = v;
    }
}

// ---------------------------------------------------------------------------
// FF head over roots (node 0 of each tree):
//   out[b] = ((h_root @ W1 + b1) @ W2 + b2) @ tail_w + tail_b
// ---------------------------------------------------------------------------
__global__ __launch_bounds__(256) void final_kernel(
    const float* __restrict__ h,
    const float* __restrict__ ff_w1, const float* __restrict__ ff_b1,
    const float* __restrict__ ff_w2, const float* __restrict__ ff_b2,
    const float* __restrict__ tail_w, const float* __restrict__ tail_b,
    float* __restrict__ out)
{
    int g    = (blockIdx.x * blockDim.x + threadIdx.x) >> 5;   // tree id
    int lane = threadIdx.x & 31;
    if (g >= BATCH) return;
    const float* r = h + (size_t)g * N_PER * HID;   // root is node 0

    float f1 = ff_b1[lane];
    #pragma unroll
    for (int kk = 0; kk < HID; ++kk) f1 += r[kk] * ff_w1[kk * HID + lane];

    float f2 = ff_b2[lane];
    #pragma unroll
    for (int kk = 0; kk < HID; ++kk) f2 += __shfl(f1, kk, 32) * ff_w2[kk * HID + lane];

    float contrib = f2 * tail_w[lane];
    #pragma unroll
    for (int off = 16; off > 0; off >>= 1) contrib += __shfl_down(contrib, off, 32);
    if (lane == 0) out[g] = contrib + tail_b[0];
}

extern "C" void kernel_launch(void* const* d_in, const int* in_sizes, int n_in,
                              void* d_out, int out_size, void* d_ws, size_t ws_size,
                              hipStream_t stream) {
    const int*   kind        = (const int*)d_in[0];
    const int*   height      = (const int*)d_in[1];
    const int*   parent      = (const int*)d_in[2];
    const int*   tok_a       = (const int*)d_in[3];
    const int*   tok_b       = (const int*)d_in[4];
    const int*   ptr_time    = (const int*)d_in[5];
    const float* first_notes = (const float*)d_in[6];
    const float* lstm_out    = (const float*)d_in[7];
    const float* embedding   = (const float*)d_in[8];
    const float* leaf_w1     = (const float*)d_in[9];
    const float* leaf_b1     = (const float*)d_in[10];
    const float* leaf_w2     = (const float*)d_in[11];
    const float* leaf_b2     = (const float*)d_in[12];
    const float* node_w      = (const float*)d_in[13];
    const float* node_b      = (const float*)d_in[14];
    const float* ptr_w       = (const float*)d_in[15];
    const float* ptr_b       = (const float*)d_in[16];
    const float* ff_w1       = (const float*)d_in[17];
    const float* ff_b1       = (const float*)d_in[18];
    const float* ff_w2       = (const float*)d_in[19];
    const float* ff_b2       = (const float*)d_in[20];
    const float* tail_w      = (const float*)d_in[21];
    const float* tail_b      = (const float*)d_in[22];

    int*   meta = (int*)d_ws;
    float* h    = (float*)((char*)d_ws + H_BYTE_OFF);   // [M_TOTAL][HID]

    build_structure<<<1, 1024, 0, stream>>>(kind, height, parent, meta);

    const int threads = 256;
    init_kernel<<<2048, threads, 0, stream>>>(
        meta, tok_a, tok_b, ptr_time, first_notes, lstm_out, embedding,
        leaf_w1, leaf_b1, leaf_w2, leaf_b2, ptr_w, ptr_b, h);

    for (int lvl = 1; lvl <= LVLS; ++lvl) {
        level_kernel<<<2048, threads, 0, stream>>>(
            meta, tok_a, tok_b, embedding, node_w, node_b, h, lvl);
    }

    final_kernel<<<(BATCH * 32 + threads - 1) / threads, threads, 0, stream>>>(
        h, ff_w1, ff_b1, ff_w2, ff_b2, tail_w, tail_b, (float*)d_out);
}

// Round 3
// 516.539 us; speedup vs baseline: 2.8317x; 1.3584x over previous
//
#include <hip/hip_runtime.h>

// Problem constants (fixed by the reference's setup_inputs)
#define BATCH   256
#define N_PER   4096
#define M_TOTAL (BATCH * N_PER)
#define EMBED   16
#define HID     32
#define NOTE    64
#define LSTM_D  64
#define T_LEN   128
#define LVLS    6
#define VOCAB   200

// ---------------------------------------------------------------------------
// ws layout:
//   meta ints:
//     [0..5]  per-tree internal-node count at level 1..6
//     [6]     per-tree kind-0 leaf count
//     [7]     per-tree kind-1 ptr count
//     [8]     per-tree internal count (all levels)
//   lists at the offsets below (one tree; structure tiled across batch)
//   floats:
//     fn_pre  [BATCH][32]      @ FN_PRE_OFF
//     rootsum [BATCH][32]      @ ROOTSUM_OFF   (zeroed每 call)
//     ptr_pre [BATCH*T_LEN][32]@ PTR_PRE_OFF
//     h       [M_TOTAL][32]    @ H_OFF  (pre-value for internal nodes until
//                                        their level fires, then final h)
// ---------------------------------------------------------------------------
#define OFF_LVL   16
#define OFF_ILIST (OFF_LVL + 6 * N_PER)
#define OFF_K0    (OFF_ILIST + N_PER)
#define OFF_K1    (OFF_K0 + N_PER)
#define OFF_COFF  (OFF_K1 + N_PER)
#define OFF_CIDX  (OFF_COFF + N_PER + 1)

#define FN_PRE_OFF   (256 * 1024)
#define ROOTSUM_OFF  (FN_PRE_OFF + 32 * 1024)
#define PTR_PRE_OFF  (512 * 1024)
#define H_OFF        (8ull * 1024 * 1024)

#define ROOT_CHUNKS 64

// ---------------------------------------------------------------------------
// Build per-tree structure: level lists, leaf lists, internal list, CSR.
// ---------------------------------------------------------------------------
__global__ __launch_bounds__(1024) void build_structure(
    const int* __restrict__ kind, const int* __restrict__ height,
    const int* __restrict__ parent, int* __restrict__ meta)
{
    __shared__ int cnt[16];
    __shared__ int deg[N_PER];
    __shared__ int part[1024];

    int t = threadIdx.x;
    if (t < 16) cnt[t] = 0;
    for (int i = t; i < N_PER; i += 1024) deg[i] = 0;
    __syncthreads();

    for (int i = t; i < N_PER; i += 1024) {
        int hgt = height[i];
        if (hgt > 0) {
            int pos = atomicAdd(&cnt[hgt - 1], 1);
            meta[OFF_LVL + (hgt - 1) * N_PER + pos] = i;
            int ip = atomicAdd(&cnt[8], 1);
            meta[OFF_ILIST + ip] = i;
        } else if (kind[i] == 0) {
            int pos = atomicAdd(&cnt[6], 1);
            meta[OFF_K0 + pos] = i;
        } else {
            int pos = atomicAdd(&cnt[7], 1);
            meta[OFF_K1 + pos] = i;
        }
        if (i != 0) atomicAdd(&deg[parent[i]], 1);   // skip root self-loop
    }
    __syncthreads();

    // exclusive prefix sum over deg[4096]
    int base = 4 * t;
    int d0 = deg[base], d1 = deg[base + 1], d2 = deg[base + 2], d3 = deg[base + 3];
    int s = d0 + d1 + d2 + d3;
    part[t] = s;
    __syncthreads();
    for (int off = 1; off < 1024; off <<= 1) {
        int v = (t >= off) ? part[t - off] : 0;
        __syncthreads();
        part[t] += v;
        __syncthreads();
    }
    int ex = (t > 0) ? part[t - 1] : 0;
    int o0 = ex, o1 = ex + d0, o2 = o1 + d1, o3 = o2 + d2;
    deg[base] = o0; deg[base + 1] = o1; deg[base + 2] = o2; deg[base + 3] = o3;
    meta[OFF_COFF + base]     = o0;
    meta[OFF_COFF + base + 1] = o1;
    meta[OFF_COFF + base + 2] = o2;
    meta[OFF_COFF + base + 3] = o3;
    if (t == 1023) meta[OFF_COFF + N_PER] = o3 + d3;
    __syncthreads();

    for (int i = t; i < N_PER; i += 1024) {
        if (i == 0) continue;
        int pos = atomicAdd(&deg[parent[i]], 1);
        meta[OFF_CIDX + pos] = i;
    }
    if (t < 16) meta[t] = cnt[t];
}

// ---------------------------------------------------------------------------
// Prep: (A) fn_pre, (B) ptr_pre GEMM, (C) leaf h, (D) internal-node pre -> h
// One 32-lane group per row; grid-stride per segment.
// ---------------------------------------------------------------------------
__global__ __launch_bounds__(256) void prep_kernel(
    const int* __restrict__ meta,
    const int* __restrict__ tok_a, const int* __restrict__ tok_b,
    const float* __restrict__ first_notes, const float* __restrict__ lstm_out,
    const float* __restrict__ embedding,
    const float* __restrict__ leaf_w1, const float* __restrict__ leaf_b1,
    const float* __restrict__ leaf_w2, const float* __restrict__ leaf_b2,
    const float* __restrict__ node_w, const float* __restrict__ node_b,
    const float* __restrict__ ptr_w, const float* __restrict__ ptr_b,
    float* __restrict__ fn_pre, float* __restrict__ ptr_pre,
    float* __restrict__ h)
{
    __shared__ float semb[VOCAB * EMBED];   // 12.8 KB
    for (int i = threadIdx.x; i < VOCAB * EMBED; i += 256) semb[i] = embedding[i];
    __syncthreads();

    int ngroups = (gridDim.x * blockDim.x) >> 5;
    int gid     = (blockIdx.x * blockDim.x + threadIdx.x) >> 5;
    int lane    = threadIdx.x & 31;

    // --- A: fn_pre[tree] = ptr_b + first_notes[tree] @ ptr_w[0:64] ---
    for (int r = gid; r < BATCH; r += ngroups) {
        const float* fn = first_notes + (size_t)r * NOTE;
        float v = ptr_b[lane];
        #pragma unroll
        for (int kk = 0; kk < NOTE; ++kk) v += fn[kk] * ptr_w[kk * HID + lane];
        fn_pre[(size_t)r * HID + lane] = v;
    }

    // --- B: ptr_pre[r] = lstm_out_flat[r] @ ptr_w[64:128] ---
    {
        int nB = BATCH * T_LEN;
        for (int r = gid; r < nB; r += ngroups) {
            const float* lo = lstm_out + (size_t)r * LSTM_D;
            float v = 0.0f;
            #pragma unroll
            for (int kk = 0; kk < LSTM_D; ++kk)
                v += lo[kk] * ptr_w[(NOTE + kk) * HID + lane];
            ptr_pre[(size_t)r * HID + lane] = v;
        }
    }

    // --- C: leaf h ---
    {
        int c0 = meta[6];
        int nC = c0 * BATCH;
        const int* k0_list = meta + OFF_K0;
        // preload lane's weight columns
        float w1a[EMBED], w1b[EMBED], w2c[HID];
        #pragma unroll
        for (int kk = 0; kk < EMBED; ++kk) {
            w1a[kk] = leaf_w1[kk * HID + lane];
            w1b[kk] = leaf_w1[(EMBED + kk) * HID + lane];
        }
        #pragma unroll
        for (int kk = 0; kk < HID; ++kk) w2c[kk] = leaf_w2[kk * HID + lane];
        for (int r = gid; r < nC; r += ngroups) {
            int tree = r / c0;
            int j    = r - tree * c0;
            int gn   = tree * N_PER + k0_list[j];
            const float* ea = semb + tok_a[gn] * EMBED;
            const float* eb = semb + tok_b[gn] * EMBED;
            float hid = leaf_b1[lane];
            #pragma unroll
            for (int kk = 0; kk < EMBED; ++kk) hid += ea[kk] * w1a[kk];
            #pragma unroll
            for (int kk = 0; kk < EMBED; ++kk) hid += eb[kk] * w1b[kk];
            float v = leaf_b2[lane];
            #pragma unroll
            for (int kk = 0; kk < HID; ++kk) v += __shfl(hid, kk, 32) * w2c[kk];
            h[(size_t)gn * HID + lane] = v;
        }
    }

    // --- D: internal-node pre = node_b + [ea,eb] @ node_w[0:32]  -> h ---
    {
        int ni = meta[8];
        int nD = ni * BATCH;
        const int* ilist = meta + OFF_ILIST;
        float wa[EMBED], wb[EMBED];
        #pragma unroll
        for (int kk = 0; kk < EMBED; ++kk) {
            wa[kk] = node_w[kk * HID + lane];
            wb[kk] = node_w[(EMBED + kk) * HID + lane];
        }
        float nb = node_b[lane];
        for (int r = gid; r < nD; r += ngroups) {
            int tree = r / ni;
            int j    = r - tree * ni;
            int gn   = tree * N_PER + ilist[j];
            const float* ea = semb + tok_a[gn] * EMBED;
            const float* eb = semb + tok_b[gn] * EMBED;
            float v = nb;
            #pragma unroll
            for (int kk = 0; kk < EMBED; ++kk) v += ea[kk] * wa[kk];
            #pragma unroll
            for (int kk = 0; kk < EMBED; ++kk) v += eb[kk] * wb[kk];
            h[(size_t)gn * HID + lane] = v;
        }
    }
}

// ---------------------------------------------------------------------------
// Ptr scatter: h[ptr node] = fn_pre[tree] + ptr_pre[tree*T_LEN + t]
// ---------------------------------------------------------------------------
__global__ __launch_bounds__(256) void ptr_scatter_kernel(
    const int* __restrict__ meta, const int* __restrict__ ptr_time,
    const float* __restrict__ fn_pre, const float* __restrict__ ptr_pre,
    float* __restrict__ h)
{
    int c1 = meta[7];
    int tot = c1 * BATCH;
    int ngroups = (gridDim.x * blockDim.x) >> 5;
    int gid     = (blockIdx.x * blockDim.x + threadIdx.x) >> 5;
    int lane    = threadIdx.x & 31;
    const int* k1_list = meta + OFF_K1;

    for (int r = gid; r < tot; r += ngroups) {
        int tree = r / c1;
        int j    = r - tree * c1;
        int gn   = tree * N_PER + k1_list[j];
        int tt   = ptr_time[gn];
        float v = fn_pre[(size_t)tree * HID + lane]
                + ptr_pre[((size_t)tree * T_LEN + tt) * HID + lane];
        h[(size_t)gn * HID + lane] = v;
    }
}

// ---------------------------------------------------------------------------
// Level pass (levels 1..5): h[gn] = relu(h[gn](=pre) + csum @ node_w[32:64])
// ---------------------------------------------------------------------------
__global__ __launch_bounds__(256) void level_kernel(
    const int* __restrict__ meta,
    const float* __restrict__ node_w,
    float* __restrict__ h, int lvl)
{
    int cnt = meta[lvl - 1];
    int tot = cnt * BATCH;
    int ngroups = (gridDim.x * blockDim.x) >> 5;
    int gid     = (blockIdx.x * blockDim.x + threadIdx.x) >> 5;
    int lane    = threadIdx.x & 31;

    const int* lvl_list  = meta + OFF_LVL + (lvl - 1) * N_PER;
    const int* child_off = meta + OFF_COFF;
    const int* child_idx = meta + OFF_CIDX;

    float wc[HID];
    #pragma unroll
    for (int kk = 0; kk < HID; ++kk) wc[kk] = node_w[(2 * EMBED + kk) * HID + lane];

    for (int r = gid; r < tot; r += ngroups) {
        int tree = r / cnt;
        int j    = r - tree * cnt;
        int node = lvl_list[j];
        int gn   = tree * N_PER + node;

        const float* hb = h + (size_t)tree * N_PER * HID;
        float csum = 0.0f;
        int e = child_off[node], e1 = child_off[node + 1];
        for (; e + 1 < e1; e += 2) {
            float a0 = hb[(size_t)child_idx[e]     * HID + lane];
            float a1 = hb[(size_t)child_idx[e + 1] * HID + lane];
            csum += a0 + a1;
        }
        if (e < e1) csum += hb[(size_t)child_idx[e] * HID + lane];

        float v = h[(size_t)gn * HID + lane];   // pre
        #pragma unroll
        for (int kk = 0; kk < HID; ++kk)
            v += __shfl(csum, kk, 32) * wc[kk];
        v = fmaxf(v, 0.0f);
        h[(size_t)gn * HID + lane] = v;
    }
}

// ---------------------------------------------------------------------------
// Root child-sum: chunked partial sums -> atomicAdd into rootsum[tree][lane]
// ---------------------------------------------------------------------------
__global__ __launch_bounds__(256) void root_gather_kernel(
    const int* __restrict__ meta, const float* __restrict__ h,
    float* __restrict__ rootsum)
{
    const int* child_off = meta + OFF_COFF;
    const int* child_idx = meta + OFF_CIDX;
    int s0 = child_off[0], e0 = child_off[1];
    int deg = e0 - s0;
    int per = (deg + ROOT_CHUNKS - 1) / ROOT_CHUNKS;

    int tot = BATCH * ROOT_CHUNKS;
    int ngroups = (gridDim.x * blockDim.x) >> 5;
    int gid     = (blockIdx.x * blockDim.x + threadIdx.x) >> 5;
    int lane    = threadIdx.x & 31;

    for (int r = gid; r < tot; r += ngroups) {
        int tree = r >> 6;           // / ROOT_CHUNKS
        int c    = r & (ROOT_CHUNKS - 1);
        int s = s0 + c * per;
        int e = s + per; if (e > e0) e = e0;
        if (s >= e) continue;
        const float* hb = h + (size_t)tree * N_PER * HID;
        float sum = 0.0f;
        for (int k = s; k < e; ++k)
            sum += hb[(size_t)child_idx[k] * HID + lane];
        atomicAdd(&rootsum[(size_t)tree * HID + lane], sum);
    }
}

// ---------------------------------------------------------------------------
// Final: finish root h, then FF head -> out[tree]
// ---------------------------------------------------------------------------
__global__ __launch_bounds__(256) void final_kernel(
    const float* __restrict__ h, const float* __restrict__ rootsum,
    const float* __restrict__ node_w,
    const float* __restrict__ ff_w1, const float* __restrict__ ff_b1,
    const float* __restrict__ ff_w2, const float* __restrict__ ff_b2,
    const float* __restrict__ tail_w, const float* __restrict__ tail_b,
    float* __restrict__ out)
{
    int g    = (blockIdx.x * blockDim.x + threadIdx.x) >> 5;   // tree id
    int lane = threadIdx.x & 31;
    if (g >= BATCH) return;

    float v  = h[(size_t)g * N_PER * HID + lane];   // pre of root (node 0)
    float cs = rootsum[(size_t)g * HID + lane];
    #pragma unroll
    for (int kk = 0; kk < HID; ++kk)
        v += __shfl(cs, kk, 32) * node_w[(2 * EMBED + kk) * HID + lane];
    v = fmaxf(v, 0.0f);

    float f1 = ff_b1[lane];
    #pragma unroll
    for (int kk = 0; kk < HID; ++kk) f1 += __shfl(v, kk, 32) * ff_w1[kk * HID + lane];

    float f2 = ff_b2[lane];
    #pragma unroll
    for (int kk = 0; kk < HID; ++kk) f2 += __shfl(f1, kk, 32) * ff_w2[kk * HID + lane];

    float contrib = f2 * tail_w[lane];
    #pragma unroll
    for (int off = 16; off > 0; off >>= 1) contrib += __shfl_down(contrib, off, 32);
    if (lane == 0) out[g] = contrib + tail_b[0];
}

extern "C" void kernel_launch(void* const* d_in, const int* in_sizes, int n_in,
                              void* d_out, int out_size, void* d_ws, size_t ws_size,
                              hipStream_t stream) {
    const int*   kind        = (const int*)d_in[0];
    const int*   height      = (const int*)d_in[1];
    const int*   parent      = (const int*)d_in[2];
    const int*   tok_a       = (const int*)d_in[3];
    const int*   tok_b       = (const int*)d_in[4];
    const int*   ptr_time    = (const int*)d_in[5];
    const float* first_notes = (const float*)d_in[6];
    const float* lstm_out    = (const float*)d_in[7];
    const float* embedding   = (const float*)d_in[8];
    const float* leaf_w1     = (const float*)d_in[9];
    const float* leaf_b1     = (const float*)d_in[10];
    const float* leaf_w2     = (const float*)d_in[11];
    const float* leaf_b2     = (const float*)d_in[12];
    const float* node_w      = (const float*)d_in[13];
    const float* node_b      = (const float*)d_in[14];
    const float* ptr_w       = (const float*)d_in[15];
    const float* ptr_b       = (const float*)d_in[16];
    const float* ff_w1       = (const float*)d_in[17];
    const float* ff_b1       = (const float*)d_in[18];
    const float* ff_w2       = (const float*)d_in[19];
    const float* ff_b2       = (const float*)d_in[20];
    const float* tail_w      = (const float*)d_in[21];
    const float* tail_b      = (const float*)d_in[22];

    char* ws = (char*)d_ws;
    int*   meta    = (int*)ws;
    float* fn_pre  = (float*)(ws + FN_PRE_OFF);
    float* rootsum = (float*)(ws + ROOTSUM_OFF);
    float* ptr_pre = (float*)(ws + PTR_PRE_OFF);
    float* h       = (float*)(ws + H_OFF);

    hipMemsetAsync(rootsum, 0, BATCH * HID * sizeof(float), stream);

    build_structure<<<1, 1024, 0, stream>>>(kind, height, parent, meta);

    prep_kernel<<<2048, 256, 0, stream>>>(
        meta, tok_a, tok_b, first_notes, lstm_out, embedding,
        leaf_w1, leaf_b1, leaf_w2, leaf_b2,
        node_w, node_b, ptr_w, ptr_b,
        fn_pre, ptr_pre, h);

    ptr_scatter_kernel<<<1024, 256, 0, stream>>>(meta, ptr_time, fn_pre, ptr_pre, h);

    for (int lvl = 1; lvl <= 5; ++lvl) {
        level_kernel<<<2048, 256, 0, stream>>>(meta, node_w, h, lvl);
    }

    root_gather_kernel<<<2048, 256, 0, stream>>>(meta, h, rootsum);

    final_kernel<<<32, 256, 0, stream>>>(
        h, rootsum, node_w, ff_w1, ff_b1, ff_w2, ff_b2, tail_w, tail_b,
        (float*)d_out);
}